// Round 24
// baseline (347.197 us; speedup 1.0000x reference)
//
#include <hip/hip_runtime.h>
#include <math.h>

#define TLEN 160000
#define NA 625
#define NB 256
#define TD 2500
#define KC 128
#define NTAP 257
#define SROWS 337
#define TWO_PI 6.283185307179586f

struct alignas(8) c2 { float x, y; };

__device__ __forceinline__ c2 cmul(c2 a, c2 b){ return c2{a.x*b.x - a.y*b.y, a.x*b.y + a.y*b.x}; }
__device__ __forceinline__ c2 cmulc(c2 a, c2 b){ return c2{a.x*b.x + a.y*b.y, a.y*b.x - a.x*b.y}; }
__device__ __forceinline__ c2 cadd(c2 a, c2 b){ return c2{a.x+b.x, a.y+b.y}; }
__device__ __forceinline__ c2 csub(c2 a, c2 b){ return c2{a.x-b.x, a.y-b.y}; }
__device__ __forceinline__ c2 cmac(c2 acc, c2 v, float wr, float wi){
  acc.x += v.x*wr - v.y*wi; acc.y += v.x*wi + v.y*wr; return acc;
}
__device__ __forceinline__ c2 cis(float ang){ c2 r; __sincosf(ang, &r.y, &r.x); return r; }
__device__ __forceinline__ int SW(int i){ return i + (i >> 4); }
__device__ __forceinline__ int SW2(int i){ return i + (i >> 2); }
__device__ __forceinline__ int SW16(int i){ return i + (i >> 4); }
__device__ __forceinline__ int SW64(int i){ return i + (i >> 6); }
__device__ __forceinline__ unsigned pack_bf(c2 z){
  unsigned xr = __float_as_uint(z.x), xi = __float_as_uint(z.y);
  xr += 0x8000u + ((xr >> 16) & 1u);
  xi += 0x8000u + ((xi >> 16) & 1u);
  return (xr >> 16) | (xi & 0xFFFF0000u);
}
__device__ __forceinline__ c2 unpack_bf(unsigned p){
  return c2{ __uint_as_float(p << 16), __uint_as_float(p & 0xFFFF0000u) };
}
__device__ __forceinline__ unsigned short f2bf(float f){
  unsigned u = __float_as_uint(f);
  u += 0x8000u + ((u >> 16) & 1u);
  return (unsigned short)(u >> 16);
}
__device__ __forceinline__ float bf2f(unsigned short h){
  return __uint_as_float(((unsigned)h) << 16);
}
__device__ __forceinline__ void wsync(){
  __builtin_amdgcn_wave_barrier();
  asm volatile("s_waitcnt lgkmcnt(0)" ::: "memory");
  __builtin_amdgcn_wave_barrier();
}

template<int S>
__device__ __forceinline__ void dft4(c2& a0, c2& a1, c2& a2, c2& a3){
  c2 t0 = cadd(a0,a2), t1 = csub(a0,a2), t2 = cadd(a1,a3), t3 = csub(a1,a3);
  float fs = (float)S;
  a0 = cadd(t0,t2); a2 = csub(t0,t2);
  a1 = c2{t1.x - fs*t3.y, t1.y + fs*t3.x};
  a3 = c2{t1.x + fs*t3.y, t1.y - fs*t3.x};
}

template<int S>
__device__ __forceinline__ void dft5(const c2 a[5], c2 b[5]){
  const float C1 = 0.30901699437494742f, C2 = -0.80901699437494745f;
  const float S1 = 0.95105651629515353f * (float)S, S2 = 0.58778525229247314f * (float)S;
  b[0] = cadd(cadd(a[0],a[1]), cadd(cadd(a[2],a[3]),a[4]));
  c2 r;
  r = a[0]; r = cmac(r,a[1],C1, S1); r = cmac(r,a[2],C2, S2); r = cmac(r,a[3],C2,-S2); r = cmac(r,a[4],C1,-S1); b[1]=r;
  r = a[0]; r = cmac(r,a[1],C2, S2); r = cmac(r,a[2],C1,-S1); r = cmac(r,a[3],C1, S1); r = cmac(r,a[4],C2,-S2); b[2]=r;
  r = a[0]; r = cmac(r,a[1],C2,-S2); r = cmac(r,a[2],C1, S1); r = cmac(r,a[3],C1,-S1); r = cmac(r,a[4],C2, S2); b[3]=r;
  r = a[0]; r = cmac(r,a[1],C1,-S1); r = cmac(r,a[2],C2,-S2); r = cmac(r,a[3],C2, S2); r = cmac(r,a[4],C1, S1); b[4]=r;
}

// ---------------- W625 global LUT init ----------------
__global__ __launch_bounds__(256) void k_wlut(c2* __restrict__ W){
  int m = blockIdx.x*256 + threadIdx.x;
  if (m < 625) W[m] = cis(TWO_PI * (float)m * (1.0f/625.0f));
}

// ---------------- tables ----------------
// tab[0..159]   stab40 : srow for M=40k conv paths (slots 64-223 of A2_40k)
// tab[160..447] stab10 : srow for M=10k conv paths (288 slots)
// tab[448..543] ftab40 : (islot | j2<<16) for dec j2<=3 FILT4 launch (96)
// tab[544..767] ftab10 : (islot | j2<<16) for dec j2>=4 FILT4 launch (224)
__device__ __forceinline__ int srowOf(int arr, int j1, int j2){
  int full = j1 >> 4;
  int cum = 16*(5*full - (full*(full-1))/2) + (j1 & 15)*(5 - full);
  int P = cum + j2 - full - 1;
  return arr*SROWS + 97 + P;
}
__global__ __launch_bounds__(256) void k_ptab(int* __restrict__ tab){
  int p = blockIdx.x*256 + threadIdx.x;
  if (p >= 768) return;
  if (p < 160){           // stab40
    int s = p, arr, j1, j2;
    if (s < 64){ arr = s>>5; int rr = s&31; j1 = rr>>1; j2 = 2 + (rr&1); }
    else {
      int q = s - 64;
      if (q < 64){ arr = q>>5; int rr = q&31; int jl = rr>>1; j2 = 2 + (rr&1); j1 = 16 + jl; }
      else { int q2 = q - 64; arr = q2>>4; int jl = q2&15; j2 = 3; j1 = 32 + jl; }
    }
    tab[p] = srowOf(arr, j1, j2);
  } else if (p < 448){    // stab10
    int s = p - 160, arr, j1, j2;
    if (s < 64){ arr = s>>5; int rr = s&31; j1 = rr>>1; j2 = 4 + (rr&1); }
    else {
      int q = s - 64;
      if (q < 192){ int c = 1 + q/64; int qq = q - (c-1)*64; arr = qq>>5; int rr = qq&31; int jl = rr>>1; j2 = 4 + (rr&1); j1 = 16*c + jl; }
      else { int q2 = q - 192; arr = q2>>4; int jl = q2&15; j2 = 5; j1 = 64 + jl; }
    }
    tab[p] = srowOf(arr, j1, j2);
  } else if (p < 544){    // ftab40
    int q = p - 448, arr, jl, j2, c;
    if (q < 64){ c = 1; arr = q>>5; int rr = q&31; jl = rr>>1; j2 = 2 + (rr&1); }
    else { int q2 = q - 64; c = 2; arr = q2>>4; jl = q2&15; j2 = 3; }
    int islot = arr*80 + 16*(c-1) + jl;
    tab[p] = islot | (j2<<16);
  } else {                // ftab10
    int q = p - 544, arr, jl, j2, c;
    if (q < 192){ c = 1 + q/64; int qq = q - (c-1)*64; arr = qq>>5; int rr = qq&31; jl = rr>>1; j2 = 4 + (rr&1); }
    else { int q2 = q - 192; c = 4; arr = q2>>4; jl = q2&15; j2 = 5; }
    int islot = arr*80 + 16*(c-1) + jl;
    tab[p] = islot | (j2<<16);
  }
}

// ---------------- 256-point row FFT (x-chain only) ----------------
template<int S, int INMODE, int OUTMODE>
__global__ __launch_bounds__(64) void k_fft256(const void* __restrict__ inp, void* __restrict__ outp){
  __shared__ c2 lds[2][272];
  int g = blockIdx.x;
  int arr = g / NA, n1 = g - arr*NA;
  int j = threadIdx.x;
  c2 v[4];
  if (INMODE == 0){
    const c2* ip = (const c2*)inp + (size_t)arr*TLEN + (size_t)n1*NB;
    #pragma unroll
    for (int q=0;q<4;q++) v[q] = ip[j + 64*q];
  } else if (INMODE == 1){
    const float* ip = (const float*)inp + (size_t)arr*TLEN + (size_t)n1*NB;
    #pragma unroll
    for (int q=0;q<4;q++) v[q] = c2{ip[j + 64*q], 0.0f};
  } else {
    const float* ip = (const float*)inp + (size_t)arr*TLEN;
    #pragma unroll
    for (int q=0;q<4;q++) v[q] = c2{ip[n1 + NA*(j + 64*q)], 0.0f};
  }
  dft4<S>(v[0],v[1],v[2],v[3]);
  #pragma unroll
  for (int r=0;r<4;r++) lds[0][SW(4*j + r)] = v[r];
  wsync();
  { // L = 4
    int k = j & 3;
    c2 w = cis((float)S * TWO_PI * (float)k * (1.0f/16.0f));
    c2 w2 = cmul(w,w), w3 = cmul(w2,w);
    v[0] = lds[0][SW(j)];
    v[1] = cmul(lds[0][SW(j+64)], w);
    v[2] = cmul(lds[0][SW(j+128)], w2);
    v[3] = cmul(lds[0][SW(j+192)], w3);
    dft4<S>(v[0],v[1],v[2],v[3]);
    int base = 4*(j-k)+k;
    #pragma unroll
    for (int r=0;r<4;r++) lds[1][SW(base + 4*r)] = v[r];
  }
  wsync();
  { // L = 16
    int k = j & 15;
    c2 w = cis((float)S * TWO_PI * (float)k * (1.0f/64.0f));
    c2 w2 = cmul(w,w), w3 = cmul(w2,w);
    v[0] = lds[1][SW(j)];
    v[1] = cmul(lds[1][SW(j+64)], w);
    v[2] = cmul(lds[1][SW(j+128)], w2);
    v[3] = cmul(lds[1][SW(j+192)], w3);
    dft4<S>(v[0],v[1],v[2],v[3]);
    int base = 4*(j-k)+k;
    #pragma unroll
    for (int r=0;r<4;r++) lds[0][SW(base + 16*r)] = v[r];
  }
  wsync();
  { // L = 64
    c2 w = cis((float)S * TWO_PI * (float)j * (1.0f/256.0f));
    c2 w2 = cmul(w,w), w3 = cmul(w2,w);
    v[0] = lds[0][SW(j)];
    v[1] = cmul(lds[0][SW(j+64)], w);
    v[2] = cmul(lds[0][SW(j+128)], w2);
    v[3] = cmul(lds[0][SW(j+192)], w3);
    dft4<S>(v[0],v[1],v[2],v[3]);
    if (OUTMODE == 0){
      c2* op = (c2*)outp + (size_t)arr*TLEN + (size_t)n1*NB;
      #pragma unroll
      for (int r=0;r<4;r++){
        int kb = j + 64*r;
        c2 tw = cis((float)S * TWO_PI * (float)(n1*kb) * (1.0f/160000.0f));
        op[kb] = cmul(v[r], tw);
      }
    } else {
      float* op = (float*)outp + (size_t)arr*TLEN + (size_t)n1*NB;
      #pragma unroll
      for (int r=0;r<4;r++){
        c2 z = v[r];
        op[j + 64*r] = sqrtf(z.x*z.x + z.y*z.y) * (1.0f/160000.0f);
      }
    }
  }
}

// ---------------- fused gather + inverse 64-FFT + abs (+ optional forward 64-FFT -> B) ------
// LDS fully c2-packed: tc = transpose buffer [16][73]; per-row scratch s0/s1 ping-pong.
#define G2CH  16
#define G2N   40
#define G2TF  73
#define G2R2  164
template<int WRITEB>
__global__ __launch_bounds__(256) void k_fft64g(const unsigned* __restrict__ inp, unsigned short* __restrict__ outp,
                                                unsigned* __restrict__ outB){
  __shared__ c2 smem[G2CH*G2TF + G2CH*G2R2];   // 1168 + 2624 = 3792 c2 = 30336 B
  c2* tc = smem;
  c2* sc = smem + G2CH*G2TF;
  int g = blockIdx.x;
  int arr = g / G2N, chunk = g - arr*G2N;
  int n1_0 = chunk*G2CH;
  int rows = 625 - n1_0; if (rows > G2CH) rows = G2CH;
  const unsigned* ip = inp + (size_t)arr*40000;
  if (rows == G2CH){
    for (int e = threadIdx.x; e < 64*G2CH; e += 256){
      int kb = e >> 4, i = e & 15;
      tc[i*G2TF + kb] = unpack_bf(ip[kb*625 + n1_0 + i]);
    }
  } else {
    for (int e = threadIdx.x; e < 64*rows; e += 256){
      int kb = e / rows, i = e - kb*rows;
      tc[i*G2TF + kb] = unpack_bf(ip[kb*625 + n1_0 + i]);
    }
  }
  __syncthreads();
  int row = threadIdx.x >> 4;
  int j   = threadIdx.x & 15;
  bool act = row < rows;
  int n1 = n1_0 + row;
  c2* s0 = sc + row*G2R2;
  c2* s1 = s0 + 82;
  c2 w4  = cis(TWO_PI * (float)(j & 3) * (1.0f/16.0f));
  c2 w4b = cmul(w4,w4), w4c = cmul(w4b,w4);
  c2 w16 = cis(TWO_PI * (float)j * (1.0f/64.0f));
  c2 w16b= cmul(w16,w16), w16c= cmul(w16b,w16);
  int b4 = 4*(j-(j&3))+(j&3);
  float av[4];
  if (act){
    c2 v[4];
    #pragma unroll
    for (int q=0;q<4;q++) v[q] = tc[row*G2TF + j + 16*q];
    dft4<1>(v[0],v[1],v[2],v[3]);
    #pragma unroll
    for (int r=0;r<4;r++) s0[SW2(4*j+r)] = v[r];
  }
  wsync();
  if (act){ // L = 4
    c2 v[4];
    v[0] = s0[SW2(j)];
    v[1] = cmul(s0[SW2(j+16)], w4);
    v[2] = cmul(s0[SW2(j+32)], w4b);
    v[3] = cmul(s0[SW2(j+48)], w4c);
    dft4<1>(v[0],v[1],v[2],v[3]);
    #pragma unroll
    for (int r=0;r<4;r++) s1[SW2(b4+4*r)] = v[r];
  }
  wsync();
  if (act){ // L = 16 + abs
    c2 v[4];
    v[0] = s1[SW2(j)];
    v[1] = cmul(s1[SW2(j+16)], w16);
    v[2] = cmul(s1[SW2(j+32)], w16b);
    v[3] = cmul(s1[SW2(j+48)], w16c);
    dft4<1>(v[0],v[1],v[2],v[3]);
    unsigned short* op = outp + (size_t)arr*40000 + (size_t)n1*64;
    #pragma unroll
    for (int r=0;r<4;r++){
      c2 z = v[r];
      av[r] = sqrtf(z.x*z.x + z.y*z.y) * (1.0f/160000.0f);
      op[j + 16*r] = f2bf(av[r]);
    }
  }
  if (WRITEB){
    wsync();
    if (act){
      c2 v[4];
      #pragma unroll
      for (int q=0;q<4;q++) v[q] = c2{av[q], 0.0f};
      dft4<-1>(v[0],v[1],v[2],v[3]);
      #pragma unroll
      for (int r=0;r<4;r++) s0[SW2(4*j+r)] = v[r];
    }
    wsync();
    if (act){
      c2 v[4];
      v[0] = s0[SW2(j)];
      v[1] = cmulc(s0[SW2(j+16)], w4);
      v[2] = cmulc(s0[SW2(j+32)], w4b);
      v[3] = cmulc(s0[SW2(j+48)], w4c);
      dft4<-1>(v[0],v[1],v[2],v[3]);
      #pragma unroll
      for (int r=0;r<4;r++) s1[SW2(b4+4*r)] = v[r];
    }
    wsync();
    if (act){
      c2 v[4];
      v[0] = s1[SW2(j)];
      v[1] = cmulc(s1[SW2(j+16)], w16);
      v[2] = cmulc(s1[SW2(j+32)], w16b);
      v[3] = cmulc(s1[SW2(j+48)], w16c);
      dft4<-1>(v[0],v[1],v[2],v[3]);
      #pragma unroll
      for (int r=0;r<4;r++){
        int kb = j + 16*r;
        c2 tw = cis(-TWO_PI * (float)(n1*kb) * (1.0f/40000.0f));
        tc[row*G2TF + kb] = cmul(v[r], tw);
      }
    }
    __syncthreads();
    unsigned* op = outB + (size_t)arr*40000;
    if (rows == G2CH){
      for (int e = threadIdx.x; e < 64*G2CH; e += 256){
        int kb = e >> 4, i = e & 15;
        op[kb*625 + n1_0 + i] = pack_bf(tc[i*G2TF + kb]);
      }
    } else {
      for (int e = threadIdx.x; e < 64*rows; e += 256){
        int kb = e / rows, i = e - kb*rows;
        op[kb*625 + n1_0 + i] = pack_bf(tc[i*G2TF + kb]);
      }
    }
  }
}

// ---------------- per-thread inverse 16-FFT + abs (M = 10000 tier) ----------------
// Input [slot][kb<16][n1<625] packed bf16; output Ur[slot][n1<625][n2<16] scalar bf16.
__global__ __launch_bounds__(256) void k_fft16g(const unsigned* __restrict__ inp, unsigned short* __restrict__ outp){
  int gid = blockIdx.x*256 + threadIdx.x;
  int s = gid / 625, n1 = gid - s*625;
  if (s >= 288) return;
  const unsigned* ip = inp + (size_t)s*10000 + n1;
  c2 A[4][4];
  #pragma unroll
  for (int k1=0;k1<4;k1++){
    c2 a0 = unpack_bf(ip[(k1   )*625]);
    c2 a1 = unpack_bf(ip[(k1+ 4)*625]);
    c2 a2 = unpack_bf(ip[(k1+ 8)*625]);
    c2 a3 = unpack_bf(ip[(k1+12)*625]);
    dft4<1>(a0,a1,a2,a3);
    A[k1][0]=a0; A[k1][1]=a1; A[k1][2]=a2; A[k1][3]=a3;
  }
  unsigned short ov[16];
  #pragma unroll
  for (int n0=0;n0<4;n0++){
    c2 w1 = cis(TWO_PI * (float)n0 * (1.0f/16.0f));
    c2 w2 = cmul(w1,w1), w3 = cmul(w2,w1);
    c2 b0 = A[0][n0];
    c2 b1 = cmul(A[1][n0], w1);
    c2 b2 = cmul(A[2][n0], w2);
    c2 b3 = cmul(A[3][n0], w3);
    dft4<1>(b0,b1,b2,b3);
    ov[n0   ] = f2bf(sqrtf(b0.x*b0.x+b0.y*b0.y)*(1.0f/160000.0f));
    ov[n0+ 4] = f2bf(sqrtf(b1.x*b1.x+b1.y*b1.y)*(1.0f/160000.0f));
    ov[n0+ 8] = f2bf(sqrtf(b2.x*b2.x+b2.y*b2.y)*(1.0f/160000.0f));
    ov[n0+12] = f2bf(sqrtf(b3.x*b3.x+b3.y*b3.y)*(1.0f/160000.0f));
  }
  unsigned short* op = outp + (size_t)s*10000 + (size_t)n1*16;
  #pragma unroll
  for (int n=0;n<16;n++) op[n] = ov[n];
}

// ---------------- 625-point row FFT (radix-5 Stockham), c2-packed LDS ----------------
// FILT: 0 none, 1 psi1 (FOLD/QPH phases), 2 psi2 (decode via launch params),
//       3 psi2 from completed 2-phase spectra (c0), 4 psi2 table-driven (dec).
template<int S, int FILT, int TW, int PIN, int POUT, int NB2, int NBI, int FOLD, int QPH>
__global__ __launch_bounds__(128) void k_fft625(const void* __restrict__ inpv, void* __restrict__ outpv,
                                                const c2* __restrict__ Wg,
                                                int j1off, int BLK, int nj2, int j2base, int istr,
                                                int scBase, int kamax, const int* __restrict__ ftab){
  __shared__ c2 l0[625], l1[625];
  int g = blockIdx.x;
  int i = g / NB2, kb = g - i*NB2;
  int j = threadIdx.x;
  const c2* ipc = (const c2*)inpv;
  const unsigned* ipu = (const unsigned*)inpv;
  size_t ibase;
  int j1 = 0, j2 = 0;
  if (FILT == 0){
    ibase = (size_t)i*(625ULL*(size_t)NB2) + (size_t)kb*NA;
  } else if (FILT == 1){
    int bt = i / BLK; j1 = j1off + (i - bt*BLK);
    ibase = (size_t)bt*(625ULL*(size_t)NBI);
  } else if (FILT == 2){
    int npb = BLK*nj2;
    int bt = i / npb, rr = i - bt*npb;
    int jloc = rr / nj2; j2 = j2base + (rr - jloc*nj2);
    int islot = bt*istr + j1off + jloc;
    ibase = (size_t)islot*(625ULL*(size_t)NBI);
  } else if (FILT == 4){
    int v = ftab[i];
    int islot = v & 0xFFFF;
    j2 = v >> 16;
    ibase = (size_t)islot*(625ULL*(size_t)NBI);
  } else { // FILT 3: completed-spectrum slot space (40000 each)
    int npb = BLK*nj2;
    int bt = i / npb, rr = i - bt*npb;
    int jloc = rr / nj2; j2 = j2base + (rr - jloc*nj2);
    int islot = bt*BLK + jloc;
    ibase = (size_t)islot*40000ULL;
  }
  float xi = 0.0f, sig = 0.0f, inv2s = 0.0f;
  int klo = 0, khi = 0;
  const float fscale = ((FILT == 2 || FILT == 4) && NBI == 64) ? 4.0f : 1.0f;
  if (FILT != 0){
    if (FILT == 1){ xi = 0.4f * exp2f(-(float)j1 * 0.0625f); sig = xi * 0.04427378243f; }
    else          { xi = 0.4f * exp2f(-(float)j2);           sig = 0.35f * xi; }
    inv2s = 0.5f / (sig*sig);
    klo = (int)((xi - 6.0f*sig) * (float)TLEN); if (klo < 0) klo = 0;
    khi = (int)((xi + 6.0f*sig) * (float)TLEN) + 1; if (khi > TLEN/2 - 1) khi = TLEN/2 - 1;
    if (FILT != 3 && !FOLD){
      if (khi > 625*NB2 - 1) khi = 625*NB2 - 1;
    }
  }
  c2 a[5], b[5];
  if (j < 125){
    if (FILT == 0){
      #pragma unroll
      for (int q=0;q<5;q++){
        size_t idx = ibase + j + 125*q;
        a[q] = PIN ? unpack_bf(ipu[idx]) : ipc[idx];
      }
      dft5<S>(a, b);
    } else if (FILT == 3){
      bool any = false;
      #pragma unroll
      for (int q=0;q<5;q++){
        int ka = j + 125*q;
        int k = kb + NB2*ka;
        float p0 = 0.0f, p1 = 0.0f;
        if (k >= klo && k <= khi){
          float d = (float)k * (1.0f/(float)TLEN) - xi;
          p0 = __expf(-d*d*inv2s); any = true;
        }
        int k1 = k + 40000;
        if (k1 >= klo && k1 <= khi){
          float d = (float)k1 * (1.0f/(float)TLEN) - xi;
          p1 = __expf(-d*d*inv2s); any = true;
        }
        c2 val = c2{0.0f, 0.0f};
        if (p0 != 0.0f || p1 != 0.0f){
          size_t kidx = (size_t)(k & 63)*625 + (size_t)(k >> 6);
          c2 B0 = unpack_bf(ipu[ibase + kidx]);
          c2 B2 = unpack_bf(ipu[ibase + 1280000ULL + kidx]);
          c2 tw = cis(-TWO_PI * (float)k * (1.0f/80000.0f));
          c2 twB2 = cmul(tw, B2);
          c2 Hk = c2{2.0f*(B0.x + twB2.x), 2.0f*(B0.y + twB2.y)};
          c2 Hb = c2{2.0f*(B0.x - twB2.x), 2.0f*(B0.y - twB2.y)};
          if (p1 != 0.0f && k > 0){
            int qi = 40000 - k;
            size_t qidx = (size_t)(qi & 63)*625 + (size_t)(qi >> 6);
            c2 C0 = unpack_bf(ipu[ibase + qidx]);
            c2 C2 = unpack_bf(ipu[ibase + 1280000ULL + qidx]);
            c2 ctwC2 = cmulc(C2, tw);
            c2 Hq = c2{2.0f*(C0.x - ctwC2.x), 2.0f*(C0.y - ctwC2.y)};
            Hb.x -= Hq.x;  Hb.y += Hq.y;
          }
          if (QPH == 0){
            val = c2{p0*Hk.x + p1*Hb.x, p0*Hk.y + p1*Hb.y};
          } else {
            c2 t2 = c2{p0*Hk.x - p1*Hb.x, p0*Hk.y - p1*Hb.y};
            val = cmulc(t2, tw);
          }
        }
        a[q] = val;
      }
      if (any){
        dft5<S>(a, b);
      } else {
        #pragma unroll
        for (int r=0;r<5;r++) b[r] = c2{0.0f,0.0f};
      }
    } else {  // FILT 1, 2 or 4
      bool any = false;
      #pragma unroll
      for (int q=0;q<5;q++){
        int ka = j + 125*q;
        int k = kb + NB2*ka;
        c2 val = c2{0.0f, 0.0f};
        if (k >= klo && k <= khi){
          size_t idx = ibase + (size_t)(k % NBI)*NA + (size_t)(k / NBI);
          val = PIN ? unpack_bf(ipu[idx]) : ipc[idx];
          float d = (float)k * (1.0f/(float)TLEN) - xi;
          float f = fscale * __expf(-d*d*inv2s);
          val.x *= f; val.y *= f;
          any = true;
        }
        if (FILT == 1 && FOLD){
          int k1 = k + 40000;
          if (k1 >= klo && k1 <= khi){
            size_t idx1 = ibase + (size_t)(k1 % NBI)*NA + (size_t)(k1 / NBI);
            c2 v1 = PIN ? unpack_bf(ipu[idx1]) : ipc[idx1];
            float d = (float)k1 * (1.0f/(float)TLEN) - xi;
            float f1 = __expf(-d*d*inv2s);
            v1.x *= f1; v1.y *= f1;
            val = QPH ? csub(val, v1) : cadd(val, v1);
            any = true;
          }
        }
        if (FILT == 1 && FOLD && QPH){
          c2 tww = cis(TWO_PI * (float)k * (1.0f/80000.0f));
          val = cmul(tww, val);
        }
        a[q] = val;
      }
      if (any){
        dft5<S>(a, b);
      } else {
        #pragma unroll
        for (int r=0;r<5;r++) b[r] = c2{0.0f,0.0f};
      }
    }
    #pragma unroll
    for (int r=0;r<5;r++) l0[5*j + r] = b[r];
  }
  __syncthreads();
  if (j < 125){ // L = 5
    int k = j % 5;
    c2 w  = Wg[25*k];  if (S<0) w.y  = -w.y;
    c2 w2 = Wg[50*k];  if (S<0) w2.y = -w2.y;
    c2 w3 = Wg[75*k];  if (S<0) w3.y = -w3.y;
    c2 w4 = Wg[100*k]; if (S<0) w4.y = -w4.y;
    a[0] = l0[j];
    a[1] = cmul(l0[j+125], w);
    a[2] = cmul(l0[j+250], w2);
    a[3] = cmul(l0[j+375], w3);
    a[4] = cmul(l0[j+500], w4);
    dft5<S>(a, b);
    int base = 5*(j-k)+k;
    #pragma unroll
    for (int r=0;r<5;r++) l1[base + 5*r] = b[r];
  }
  __syncthreads();
  if (j < 125){ // L = 25
    int k = j % 25;
    c2 w  = Wg[5*k];   if (S<0) w.y  = -w.y;
    c2 w2 = Wg[10*k];  if (S<0) w2.y = -w2.y;
    c2 w3 = Wg[15*k];  if (S<0) w3.y = -w3.y;
    c2 w4 = Wg[20*k];  if (S<0) w4.y = -w4.y;
    a[0] = l1[j];
    a[1] = cmul(l1[j+125], w);
    a[2] = cmul(l1[j+250], w2);
    a[3] = cmul(l1[j+375], w3);
    a[4] = cmul(l1[j+500], w4);
    dft5<S>(a, b);
    int base = 5*(j-k)+k;
    #pragma unroll
    for (int r=0;r<5;r++) l0[base + 25*r] = b[r];
  }
  __syncthreads();
  if (j < 125){ // L = 125
    c2 w = Wg[j]; if (S<0) w.y = -w.y;
    c2 w2 = cmul(w,w), w3 = cmul(w2,w), w4 = cmul(w2,w2);
    a[0] = l0[j];
    a[1] = cmul(l0[j+125], w);
    a[2] = cmul(l0[j+250], w2);
    a[3] = cmul(l0[j+375], w3);
    a[4] = cmul(l0[j+500], w4);
    dft5<S>(a, b);
    size_t obase = (size_t)(scBase + i)*(625ULL*(size_t)NB2) + (size_t)kb*NA;
    if (TW){
      const float invM = 1.0f/(625.0f*(float)NB2);
      c2 twb = cis((float)S * TWO_PI * (float)(j*kb)   * invM);
      c2 tws = cis((float)S * TWO_PI * (float)(125*kb) * invM);
      #pragma unroll
      for (int r=0;r<5;r++){
        int n1 = j + 125*r;
        c2 z = cmul(b[r], twb);
        if (POUT) ((unsigned*)outpv)[obase + n1] = pack_bf(z);
        else      ((c2*)outpv)[obase + n1] = z;
        twb = cmul(twb, tws);
      }
    } else {
      #pragma unroll
      for (int r=0;r<5;r++){
        int n1 = j + 125*r;
        if (n1 <= kamax){
          if (POUT) ((unsigned*)outpv)[obase + n1] = pack_bf(b[r]);
          else      ((c2*)outpv)[obase + n1] = b[r];
        }
      }
    }
  }
}

// ---------------- complex transpose (x-chain only) ----------------
__global__ __launch_bounds__(256) void k_transpose(const c2* __restrict__ in, c2* __restrict__ out,
                                                   int R, int C, int tilesR, int tilesC){
  __shared__ c2 tile[32][33];
  int bi = blockIdx.x;
  int arr = bi / (tilesR*tilesC);
  int tt = bi - arr*(tilesR*tilesC);
  int tr = tt / tilesC, tc = tt - tr*tilesC;
  const c2* ip = in + (size_t)arr*TLEN;
  c2* op = out + (size_t)arr*TLEN;
  int tx = threadIdx.x & 31, ty = threadIdx.x >> 5;
  #pragma unroll
  for (int i=0;i<4;i++){
    int r = tr*32 + ty + i*8, cc = tc*32 + tx;
    if (r < R && cc < C) tile[ty+i*8][tx] = ip[(size_t)r*C + cc];
  }
  __syncthreads();
  #pragma unroll
  for (int i=0;i<4;i++){
    int r = tc*32 + ty + i*8, cc = tr*32 + tx;
    if (r < C && cc < R) op[(size_t)r*R + cc] = tile[tx][ty+i*8];
  }
}

// ---------------- Gaussian lowpass + decimate-by-64, natural layout (S0 only) ----------------
__global__ __launch_bounds__(256) void k_conv(const float* __restrict__ inp, float* __restrict__ S){
  __shared__ float w[NTAP];
  for (int i=threadIdx.x; i<NTAP; i+=256){
    float d = (float)(i - KC);
    w[i] = 0.015666427f * __expf(-7.7106284e-4f * d * d);
  }
  __syncthreads();
  int g = blockIdx.x;
  int arr = g / 10;
  int t = (g - arr*10)*256 + threadIdx.x;
  if (t >= TD) return;
  int srow = arr * SROWS;
  const float* ip = inp + (size_t)arr*TLEN;
  float acc = 0.0f;
  int n = 64*t - KC; if (n < 0) n += TLEN;
  for (int m=0;m<NTAP;m++){
    acc += ip[n] * w[m];
    n++; if (n == TLEN) n = 0;
  }
  S[(size_t)srow*TD + t] = acc;
}

// ---------------- decimated conv (D=4): input Ur_dec[n1<625][n2<64], M=40000 ----------------
#define C2NU  5000
#define C2USZ 5312
template<int MODE>
__global__ __launch_bounds__(256) void k_conv2d(const unsigned short* __restrict__ inp, float* __restrict__ S,
                                                int j1off, int BLK, const int* __restrict__ srowTab){
  __shared__ float u[C2USZ];
  __shared__ float w[72];
  if (threadIdx.x < 65){
    float d = 4.0f * (float)((int)threadIdx.x - 32);
    w[threadIdx.x] = 0.062665708f * __expf(-7.7106284e-4f * d * d);
  }
  int g = blockIdx.x;
  int arr = g / 10;
  int b = g - arr*10;
  int mlo = 4000*b - 32;
  int n2_0 = (mlo >= 0) ? (mlo/625) : -1;
  const unsigned short* ip = inp + (size_t)arr*40000;
  for (int e = threadIdx.x; e < C2NU; e += 256){
    int n1 = e >> 3, c = e & 7;
    int n2 = (n2_0 + c) & 63;
    u[SW16(n1 + 625*c)] = bf2f(ip[n1*64 + n2]);
  }
  __syncthreads();
  int tl = threadIdx.x;
  if (tl >= 250) return;
  int t = 250*b + tl;
  int srow;
  if (MODE == 1){
    int a2 = arr / BLK; int j1 = j1off + (arr - a2*BLK);
    srow = a2*SROWS + 1 + j1;
  } else {
    srow = srowTab[arr];
  }
  int base = (4000*b - 32 - 625*n2_0) + 16*tl;
  float acc = 0.0f;
  #pragma unroll 5
  for (int m=0;m<65;m++){
    acc += u[SW16(base + m)] * w[m];
  }
  S[(size_t)srow*TD + t] = acc;
}

// ---------------- decimated conv (D=16): input Ur10k[n1<625][n2<16], M=10000 ----------------
#define CQ_USZ 2344
__global__ __launch_bounds__(256) void k_conv2q(const unsigned short* __restrict__ inp, float* __restrict__ S,
                                                const int* __restrict__ srowTab){
  __shared__ float u[CQ_USZ];
  __shared__ float w[20];
  if (threadIdx.x < 17){
    float d = 16.0f * (float)((int)threadIdx.x - 8);
    w[threadIdx.x] = 0.25066283f * __expf(-7.7106284e-4f * d * d);
  }
  int g = blockIdx.x;
  int slot = g / 10;
  int b = g - slot*10;
  int mlo = 1000*b - 8;
  int n2_0 = (mlo >= 0) ? (mlo/625) : -1;
  const unsigned short* ip = inp + (size_t)slot*10000;
  for (int e = threadIdx.x; e < 1875; e += 256){
    int c = e / 625, n1 = e - c*625;
    int n2 = (n2_0 + c) & 15;
    u[SW2(n1 + 625*c)] = bf2f(ip[n1*16 + n2]);
  }
  __syncthreads();
  int tl = threadIdx.x;
  if (tl >= 250) return;
  int t = 250*b + tl;
  int srow = srowTab[slot];
  int base = (1000*b - 8 - 625*n2_0) + 4*tl;
  float acc = 0.0f;
  #pragma unroll
  for (int m=0;m<17;m++){
    acc += u[SW2(base + m)] * w[m];
  }
  S[(size_t)srow*TD + t] = acc;
}

// ---------------- 2-phase decimated conv (D=2) for c0 j2=1 paths ----------------
__global__ __launch_bounds__(256) void k_conv2e(const unsigned short* __restrict__ Ue,
                                                const unsigned short* __restrict__ Uo,
                                                float* __restrict__ S){
  __shared__ float ue[C2USZ], uo[C2USZ];
  __shared__ float we[72], wo[72];
  if (threadIdx.x < 65){
    float d = 4.0f*(float)((int)threadIdx.x) - 128.0f;
    we[threadIdx.x] = 0.031332854f * __expf(-7.7106284e-4f * d * d);
  }
  if (threadIdx.x >= 128 && threadIdx.x < 192){
    int h = (int)threadIdx.x - 128;
    float d = 4.0f*(float)h - 126.0f;
    wo[h] = 0.031332854f * __expf(-7.7106284e-4f * d * d);
  }
  int g = blockIdx.x;
  int path = g / 10;
  int b = g - path*10;
  int mlo = 4000*b - 32;
  int n2_0 = (mlo >= 0) ? (mlo/625) : -1;
  const unsigned short* ipe = Ue + (size_t)path*40000;
  const unsigned short* ipo = Uo + (size_t)path*40000;
  for (int e = threadIdx.x; e < C2NU; e += 256){
    int n1 = e >> 3, c = e & 7;
    int n2 = (n2_0 + c) & 63;
    ue[SW16(n1 + 625*c)] = bf2f(ipe[n1*64 + n2]);
    uo[SW16(n1 + 625*c)] = bf2f(ipo[n1*64 + n2]);
  }
  __syncthreads();
  int tl = threadIdx.x;
  if (tl >= 250) return;
  int t = 250*b + tl;
  int arr = path >> 4;
  int j1  = path & 15;
  int srow = arr*SROWS + 97 + 5*j1;
  int base = (4000*b - 32 - 625*n2_0) + 16*tl;
  float acc = 0.0f;
  #pragma unroll 5
  for (int m=0;m<65;m++){
    acc += ue[SW16(base + m)] * we[m];
  }
  #pragma unroll 4
  for (int m=0;m<64;m++){
    acc += uo[SW16(base + m)] * wo[m];
  }
  S[(size_t)srow*TD + t] = acc;
}

// ---------------- global min/max + finalize ----------------
__global__ __launch_bounds__(256) void k_minmax1(const float* __restrict__ S, int n, float* pmn, float* pmx){
  __shared__ float smn[256], smx[256];
  float mn = 3.4028235e38f, mx = -3.4028235e38f;
  for (size_t i = (size_t)blockIdx.x*256 + threadIdx.x; i < (size_t)n; i += (size_t)gridDim.x*256){
    float v = S[i]; mn = fminf(mn,v); mx = fmaxf(mx,v);
  }
  smn[threadIdx.x]=mn; smx[threadIdx.x]=mx; __syncthreads();
  for (int s=128;s>0;s>>=1){
    if ((int)threadIdx.x < s){
      smn[threadIdx.x]=fminf(smn[threadIdx.x],smn[threadIdx.x+s]);
      smx[threadIdx.x]=fmaxf(smx[threadIdx.x],smx[threadIdx.x+s]);
    }
    __syncthreads();
  }
  if (threadIdx.x==0){ pmn[blockIdx.x]=smn[0]; pmx[blockIdx.x]=smx[0]; }
}
__global__ __launch_bounds__(256) void k_minmax2(const float* __restrict__ pmn, const float* __restrict__ pmx,
                                                 int nb, float* scal){
  __shared__ float smn[256], smx[256];
  float mn = 3.4028235e38f, mx = -3.4028235e38f;
  for (int i = threadIdx.x; i < nb; i += 256){ mn = fminf(mn,pmn[i]); mx = fmaxf(mx,pmx[i]); }
  smn[threadIdx.x]=mn; smx[threadIdx.x]=mx; __syncthreads();
  for (int s=128;s>0;s>>=1){
    if ((int)threadIdx.x < s){
      smn[threadIdx.x]=fminf(smn[threadIdx.x],smn[threadIdx.x+s]);
      smx[threadIdx.x]=fmaxf(smx[threadIdx.x],smx[threadIdx.x+s]);
    }
    __syncthreads();
  }
  if (threadIdx.x==0){ scal[0]=smn[0]; scal[1]=smx[0]; }
}
__global__ __launch_bounds__(256) void k_final(const float* __restrict__ S, const float* __restrict__ scal,
                                               float* __restrict__ out, int n){
  int i = blockIdx.x*256 + threadIdx.x;
  if (i >= n) return;
  float mn = scal[0];
  float r = scal[1] - mn;
  if (r == 0.0f) r = 1.0f;
  int half = SROWS*TD;
  int a = i / half; int rest = i - a*half;
  out[i] = (S[(size_t)(a & 1)*half + rest] - mn) / r;
}

extern "C" void kernel_launch(void* const* d_in, const int* in_sizes, int n_in,
                              void* d_out, int out_size, void* d_ws, size_t ws_size,
                              hipStream_t stream){
  (void)in_sizes; (void)n_in;
  const float* x = (const float*)d_in[0];

  // Xf 2.56 + A1 35.84 + B 35.84 + U1h 35.84 + A2 47.36 + Ur 23.68 + Sb 6.74 + misc
  {
    size_t need = 2560000ULL + 35840000ULL + 35840000ULL + 35840000ULL
                + 47360000ULL + 23680000ULL + 6740000ULL + 65536ULL;
    if (ws_size < need) return;
  }

  char* p = (char*)d_ws;
  auto carve = [&](size_t bytes)->void*{ void* r = (void*)p; p += (bytes + 255) & ~(size_t)255; return r; };
  c2*             Xf  = (c2*)carve(2ULL*TLEN*sizeof(c2));
  unsigned*       A1  = (unsigned*)carve(224ULL*40000*4);    // 0-31 c0e, 32-63 c0o, 64-223 dec
  unsigned*       B   = (unsigned*)carve(224ULL*40000*4);    // first-stage fwd, same slot map
  unsigned*       U1h = (unsigned*)carve(224ULL*40000*4);    // completed spectra, same slot map
  unsigned*       A2  = (unsigned*)carve(224ULL*40000*4 + 288ULL*10000*4); // 40k tier + 10k tier
  unsigned short* Ur  = (unsigned short*)carve(224ULL*40000*2 + 288ULL*10000*2);
  float*          Sb  = (float*)carve(2ULL*SROWS*TD*sizeof(float));
  c2*             Wg  = (c2*)carve(625*sizeof(c2));
  int*            tab = (int*)carve(768*4);
  float*          pmn = (float*)carve(512*4);
  float*          pmx = (float*)carve(512*4);
  float*          scal = (float*)carve(256);

  unsigned*       A2t = A2 + 224ULL*40000;        // 10k tier spectra
  unsigned short* Urt = Ur + 224ULL*40000;        // 10k tier magnitudes

  k_wlut<<<3, 256, 0, stream>>>(Wg);
  k_ptab<<<3, 256, 0, stream>>>(tab);

  // ---- forward FFT of x -> Xf (A2 reused as c2 scratch; U1h as c2 scratch) ----
  k_fft256<-1,2,0><<<2*NA, 64, 0, stream>>>((const void*)x, (void*)A2);
  k_transpose<<<2*20*8, 256, 0, stream>>>((c2*)A2, (c2*)U1h, NA, NB, 20, 8);
  k_fft625<-1,0,0,0,0,256,256,0,0><<<2*NB, 128, 0, stream>>>((const void*)U1h, (void*)Xf, Wg, 0,0,0,0,0,0, 314, nullptr);
  // ---- S0 ----
  k_conv<<<2*10, 256, 0, stream>>>(x, Sb);

  // ================= order-1 (all decimated) =================
  k_fft625<1,1,1,0,1,64,256,1,0><<<32*64, 128, 0, stream>>>((const void*)Xf, (void*)A1, Wg, 0,16,0,0,0,0, 624, nullptr);
  k_fft625<1,1,1,0,1,64,256,1,1><<<32*64, 128, 0, stream>>>((const void*)Xf, (void*)A1, Wg, 0,16,0,0,0,32, 624, nullptr);
  k_fft625<1,1,1,0,1,64,256,0,0><<<160*64, 128, 0, stream>>>((const void*)Xf, (void*)A1, Wg, 16,80,0,0,0,64, 624, nullptr);
  k_fft64g<1><<<224*G2N, 256, 0, stream>>>(A1, Ur, B);
  k_conv2d<1><<<32*10, 256, 0, stream>>>(Ur, Sb, 0, 16, (const int*)nullptr);
  k_conv2d<1><<<160*10, 256, 0, stream>>>(Ur + 64ULL*40000, Sb, 16, 80, (const int*)nullptr);
  // second stage forward over ALL 224 slots -> completed spectra in U1h
  k_fft625<-1,0,0,1,1,64,64,0,0><<<224*64, 128, 0, stream>>>((const void*)B, (void*)U1h, Wg, 0,0,0,0,0,0, 624, nullptr);

  // ================= order-2, M=40000 tier (j2 <= 3) =================
  // dec j2<=3 (96 paths, table) -> A2 slots 128-223
  k_fft625<1,4,1,1,1,64,64,0,0><<<96*64, 128, 0, stream>>>((const void*)(U1h + 64ULL*40000), (void*)A2, Wg,
                                                           0,0,0,0,0, 128, 624, tab + 448);
  // c0 j2 in {2,3} -> slots 64-127
  k_fft625<1,3,1,1,1,64,64,0,0><<<64*64, 128, 0, stream>>>((const void*)U1h, (void*)A2, Wg, 0,16,2,2,16, 64, 624, nullptr);
  // c0 j2=1, two phases -> slots 0-31 / 32-63
  k_fft625<1,3,1,1,1,64,64,0,0><<<32*64, 128, 0, stream>>>((const void*)U1h, (void*)A2, Wg, 0,16,1,1,16, 0, 624, nullptr);
  k_fft625<1,3,1,1,1,64,64,0,1><<<32*64, 128, 0, stream>>>((const void*)U1h, (void*)A2, Wg, 0,16,1,1,16, 32, 624, nullptr);
  k_fft64g<0><<<224*G2N, 256, 0, stream>>>(A2, Ur, (unsigned*)nullptr);
  k_conv2e<<<32*10, 256, 0, stream>>>(Ur, Ur + 32ULL*40000, Sb);
  k_conv2d<3><<<160*10, 256, 0, stream>>>(Ur + 64ULL*40000, Sb, 0, 0, tab);

  // ================= order-2, M=10000 tier (j2 >= 4) =================
  // c0 j2 in {4,5} -> 10k slots 0-63
  k_fft625<1,3,1,1,1,16,64,0,0><<<64*16, 128, 0, stream>>>((const void*)U1h, (void*)A2t, Wg, 0,16,2,4,16, 0, 624, nullptr);
  // dec j2>=4 (224 paths, table) -> 10k slots 64-287
  k_fft625<1,4,1,1,1,16,64,0,0><<<224*16, 128, 0, stream>>>((const void*)(U1h + 64ULL*40000), (void*)A2t, Wg,
                                                            0,0,0,0,0, 64, 624, tab + 544);
  k_fft16g<<<704, 256, 0, stream>>>(A2t, Urt);
  k_conv2q<<<288*10, 256, 0, stream>>>(Urt, Sb, tab + 160);

  // ---- global min-max normalize (standardize cancels) + tile(3,1,1) ----
  k_minmax1<<<512, 256, 0, stream>>>(Sb, 2*SROWS*TD, pmn, pmx);
  k_minmax2<<<1, 256, 0, stream>>>(pmn, pmx, 512, scal);
  k_final<<<(out_size+255)/256, 256, 0, stream>>>(Sb, scal, (float*)d_out, out_size);
}

// Round 25
// 347.017 us; speedup vs baseline: 1.0005x; 1.0005x over previous
//
#include <hip/hip_runtime.h>
#include <math.h>

#define TLEN 160000
#define NA 625
#define NB 256
#define TD 2500
#define KC 128
#define NTAP 257
#define SROWS 337
#define TWO_PI 6.283185307179586f

struct alignas(8) c2 { float x, y; };

__device__ __forceinline__ c2 cmul(c2 a, c2 b){ return c2{a.x*b.x - a.y*b.y, a.x*b.y + a.y*b.x}; }
__device__ __forceinline__ c2 cmulc(c2 a, c2 b){ return c2{a.x*b.x + a.y*b.y, a.y*b.x - a.x*b.y}; }
__device__ __forceinline__ c2 cadd(c2 a, c2 b){ return c2{a.x+b.x, a.y+b.y}; }
__device__ __forceinline__ c2 csub(c2 a, c2 b){ return c2{a.x-b.x, a.y-b.y}; }
__device__ __forceinline__ c2 cmac(c2 acc, c2 v, float wr, float wi){
  acc.x += v.x*wr - v.y*wi; acc.y += v.x*wi + v.y*wr; return acc;
}
__device__ __forceinline__ c2 cis(float ang){ c2 r; __sincosf(ang, &r.y, &r.x); return r; }
__device__ __forceinline__ int SW(int i){ return i + (i >> 4); }
__device__ __forceinline__ int SW2(int i){ return i + (i >> 2); }
__device__ __forceinline__ int SW16(int i){ return i + (i >> 4); }
__device__ __forceinline__ int SW64(int i){ return i + (i >> 6); }
__device__ __forceinline__ unsigned pack_bf(c2 z){
  unsigned xr = __float_as_uint(z.x), xi = __float_as_uint(z.y);
  xr += 0x8000u + ((xr >> 16) & 1u);
  xi += 0x8000u + ((xi >> 16) & 1u);
  return (xr >> 16) | (xi & 0xFFFF0000u);
}
__device__ __forceinline__ c2 unpack_bf(unsigned p){
  return c2{ __uint_as_float(p << 16), __uint_as_float(p & 0xFFFF0000u) };
}
__device__ __forceinline__ unsigned short f2bf(float f){
  unsigned u = __float_as_uint(f);
  u += 0x8000u + ((u >> 16) & 1u);
  return (unsigned short)(u >> 16);
}
__device__ __forceinline__ float bf2f(unsigned short h){
  return __uint_as_float(((unsigned)h) << 16);
}
__device__ __forceinline__ void wsync(){
  __builtin_amdgcn_wave_barrier();
  asm volatile("s_waitcnt lgkmcnt(0)" ::: "memory");
  __builtin_amdgcn_wave_barrier();
}

template<int S>
__device__ __forceinline__ void dft4(c2& a0, c2& a1, c2& a2, c2& a3){
  c2 t0 = cadd(a0,a2), t1 = csub(a0,a2), t2 = cadd(a1,a3), t3 = csub(a1,a3);
  float fs = (float)S;
  a0 = cadd(t0,t2); a2 = csub(t0,t2);
  a1 = c2{t1.x - fs*t3.y, t1.y + fs*t3.x};
  a3 = c2{t1.x + fs*t3.y, t1.y - fs*t3.x};
}

template<int S>
__device__ __forceinline__ void dft5(const c2 a[5], c2 b[5]){
  const float C1 = 0.30901699437494742f, C2 = -0.80901699437494745f;
  const float S1 = 0.95105651629515353f * (float)S, S2 = 0.58778525229247314f * (float)S;
  b[0] = cadd(cadd(a[0],a[1]), cadd(cadd(a[2],a[3]),a[4]));
  c2 r;
  r = a[0]; r = cmac(r,a[1],C1, S1); r = cmac(r,a[2],C2, S2); r = cmac(r,a[3],C2,-S2); r = cmac(r,a[4],C1,-S1); b[1]=r;
  r = a[0]; r = cmac(r,a[1],C2, S2); r = cmac(r,a[2],C1,-S1); r = cmac(r,a[3],C1, S1); r = cmac(r,a[4],C2,-S2); b[2]=r;
  r = a[0]; r = cmac(r,a[1],C2,-S2); r = cmac(r,a[2],C1, S1); r = cmac(r,a[3],C1,-S1); r = cmac(r,a[4],C2, S2); b[3]=r;
  r = a[0]; r = cmac(r,a[1],C1,-S1); r = cmac(r,a[2],C2,-S2); r = cmac(r,a[3],C2, S2); r = cmac(r,a[4],C1, S1); b[4]=r;
}

// ---------------- W625 global LUT init ----------------
__global__ __launch_bounds__(256) void k_wlut(c2* __restrict__ W){
  int m = blockIdx.x*256 + threadIdx.x;
  if (m < 625) W[m] = cis(TWO_PI * (float)m * (1.0f/625.0f));
}

// ---------------- tables ----------------
// tab[0..159]   stab40 : srow for M=40k conv paths (slots 64-223 of A2_40k)
// tab[160..447] stab10 : srow for M=10k conv paths (288 slots)
// tab[448..543] ftab40 : (islot | j2<<16) for dec j2<=3 FILT4 launch (96)
// tab[544..767] ftab10 : (islot | j2<<16) for dec j2>=4 FILT4 launch (224)
__device__ __forceinline__ int srowOf(int arr, int j1, int j2){
  int full = j1 >> 4;
  int cum = 16*(5*full - (full*(full-1))/2) + (j1 & 15)*(5 - full);
  int P = cum + j2 - full - 1;
  return arr*SROWS + 97 + P;
}
__global__ __launch_bounds__(256) void k_ptab(int* __restrict__ tab){
  int p = blockIdx.x*256 + threadIdx.x;
  if (p >= 768) return;
  if (p < 160){           // stab40
    int s = p, arr, j1, j2;
    if (s < 64){ arr = s>>5; int rr = s&31; j1 = rr>>1; j2 = 2 + (rr&1); }
    else {
      int q = s - 64;
      if (q < 64){ arr = q>>5; int rr = q&31; int jl = rr>>1; j2 = 2 + (rr&1); j1 = 16 + jl; }
      else { int q2 = q - 64; arr = q2>>4; int jl = q2&15; j2 = 3; j1 = 32 + jl; }
    }
    tab[p] = srowOf(arr, j1, j2);
  } else if (p < 448){    // stab10
    int s = p - 160, arr, j1, j2;
    if (s < 64){ arr = s>>5; int rr = s&31; j1 = rr>>1; j2 = 4 + (rr&1); }
    else {
      int q = s - 64;
      if (q < 192){ int c = 1 + q/64; int qq = q - (c-1)*64; arr = qq>>5; int rr = qq&31; int jl = rr>>1; j2 = 4 + (rr&1); j1 = 16*c + jl; }
      else { int q2 = q - 192; arr = q2>>4; int jl = q2&15; j2 = 5; j1 = 64 + jl; }
    }
    tab[p] = srowOf(arr, j1, j2);
  } else if (p < 544){    // ftab40
    int q = p - 448, arr, jl, j2, c;
    if (q < 64){ c = 1; arr = q>>5; int rr = q&31; jl = rr>>1; j2 = 2 + (rr&1); }
    else { int q2 = q - 64; c = 2; arr = q2>>4; jl = q2&15; j2 = 3; }
    int islot = arr*80 + 16*(c-1) + jl;
    tab[p] = islot | (j2<<16);
  } else {                // ftab10
    int q = p - 544, arr, jl, j2, c;
    if (q < 192){ c = 1 + q/64; int qq = q - (c-1)*64; arr = qq>>5; int rr = qq&31; jl = rr>>1; j2 = 4 + (rr&1); }
    else { int q2 = q - 192; c = 4; arr = q2>>4; jl = q2&15; j2 = 5; }
    int islot = arr*80 + 16*(c-1) + jl;
    tab[p] = islot | (j2<<16);
  }
}

// ---------------- 256-point row FFT (x-chain only) ----------------
template<int S, int INMODE, int OUTMODE>
__global__ __launch_bounds__(64) void k_fft256(const void* __restrict__ inp, void* __restrict__ outp){
  __shared__ c2 lds[2][272];
  int g = blockIdx.x;
  int arr = g / NA, n1 = g - arr*NA;
  int j = threadIdx.x;
  c2 v[4];
  if (INMODE == 0){
    const c2* ip = (const c2*)inp + (size_t)arr*TLEN + (size_t)n1*NB;
    #pragma unroll
    for (int q=0;q<4;q++) v[q] = ip[j + 64*q];
  } else if (INMODE == 1){
    const float* ip = (const float*)inp + (size_t)arr*TLEN + (size_t)n1*NB;
    #pragma unroll
    for (int q=0;q<4;q++) v[q] = c2{ip[j + 64*q], 0.0f};
  } else {
    const float* ip = (const float*)inp + (size_t)arr*TLEN;
    #pragma unroll
    for (int q=0;q<4;q++) v[q] = c2{ip[n1 + NA*(j + 64*q)], 0.0f};
  }
  dft4<S>(v[0],v[1],v[2],v[3]);
  #pragma unroll
  for (int r=0;r<4;r++) lds[0][SW(4*j + r)] = v[r];
  wsync();
  { // L = 4
    int k = j & 3;
    c2 w = cis((float)S * TWO_PI * (float)k * (1.0f/16.0f));
    c2 w2 = cmul(w,w), w3 = cmul(w2,w);
    v[0] = lds[0][SW(j)];
    v[1] = cmul(lds[0][SW(j+64)], w);
    v[2] = cmul(lds[0][SW(j+128)], w2);
    v[3] = cmul(lds[0][SW(j+192)], w3);
    dft4<S>(v[0],v[1],v[2],v[3]);
    int base = 4*(j-k)+k;
    #pragma unroll
    for (int r=0;r<4;r++) lds[1][SW(base + 4*r)] = v[r];
  }
  wsync();
  { // L = 16
    int k = j & 15;
    c2 w = cis((float)S * TWO_PI * (float)k * (1.0f/64.0f));
    c2 w2 = cmul(w,w), w3 = cmul(w2,w);
    v[0] = lds[1][SW(j)];
    v[1] = cmul(lds[1][SW(j+64)], w);
    v[2] = cmul(lds[1][SW(j+128)], w2);
    v[3] = cmul(lds[1][SW(j+192)], w3);
    dft4<S>(v[0],v[1],v[2],v[3]);
    int base = 4*(j-k)+k;
    #pragma unroll
    for (int r=0;r<4;r++) lds[0][SW(base + 16*r)] = v[r];
  }
  wsync();
  { // L = 64
    c2 w = cis((float)S * TWO_PI * (float)j * (1.0f/256.0f));
    c2 w2 = cmul(w,w), w3 = cmul(w2,w);
    v[0] = lds[0][SW(j)];
    v[1] = cmul(lds[0][SW(j+64)], w);
    v[2] = cmul(lds[0][SW(j+128)], w2);
    v[3] = cmul(lds[0][SW(j+192)], w3);
    dft4<S>(v[0],v[1],v[2],v[3]);
    if (OUTMODE == 0){
      c2* op = (c2*)outp + (size_t)arr*TLEN + (size_t)n1*NB;
      #pragma unroll
      for (int r=0;r<4;r++){
        int kb = j + 64*r;
        c2 tw = cis((float)S * TWO_PI * (float)(n1*kb) * (1.0f/160000.0f));
        op[kb] = cmul(v[r], tw);
      }
    } else {
      float* op = (float*)outp + (size_t)arr*TLEN + (size_t)n1*NB;
      #pragma unroll
      for (int r=0;r<4;r++){
        c2 z = v[r];
        op[j + 64*r] = sqrtf(z.x*z.x + z.y*z.y) * (1.0f/160000.0f);
      }
    }
  }
}

// ---------------- fused gather + inverse 64-FFT + abs (+ optional forward 64-FFT -> B) ------
// Single per-row scratch buffer (82 c2), stage = {read -> wsync -> write -> wsync}.
// Safe: all 16 row-threads are in one wave; each stage's writes are a bijection of the row.
#define G2CH  16
#define G2N   40
#define G2TF  73
#define G2SR  82
template<int WRITEB>
__global__ __launch_bounds__(256) void k_fft64g(const unsigned* __restrict__ inp, unsigned short* __restrict__ outp,
                                                unsigned* __restrict__ outB){
  __shared__ c2 smem[G2CH*G2TF + G2CH*G2SR];   // 1168 + 1312 = 2480 c2 = 19840 B
  c2* tc = smem;
  c2* sc = smem + G2CH*G2TF;
  int g = blockIdx.x;
  int arr = g / G2N, chunk = g - arr*G2N;
  int n1_0 = chunk*G2CH;
  int rows = 625 - n1_0; if (rows > G2CH) rows = G2CH;
  const unsigned* ip = inp + (size_t)arr*40000;
  if (rows == G2CH){
    for (int e = threadIdx.x; e < 64*G2CH; e += 256){
      int kb = e >> 4, i = e & 15;
      tc[i*G2TF + kb] = unpack_bf(ip[kb*625 + n1_0 + i]);
    }
  } else {
    for (int e = threadIdx.x; e < 64*rows; e += 256){
      int kb = e / rows, i = e - kb*rows;
      tc[i*G2TF + kb] = unpack_bf(ip[kb*625 + n1_0 + i]);
    }
  }
  __syncthreads();
  int row = threadIdx.x >> 4;
  int j   = threadIdx.x & 15;
  bool act = row < rows;
  int n1 = n1_0 + row;
  c2* s = sc + row*G2SR;
  c2 w4  = cis(TWO_PI * (float)(j & 3) * (1.0f/16.0f));
  c2 w4b = cmul(w4,w4), w4c = cmul(w4b,w4);
  c2 w16 = cis(TWO_PI * (float)j * (1.0f/64.0f));
  c2 w16b= cmul(w16,w16), w16c= cmul(w16b,w16);
  int b4 = 4*(j-(j&3))+(j&3);
  float av[4];
  c2 v[4];
  if (act){
    #pragma unroll
    for (int q=0;q<4;q++) v[q] = tc[row*G2TF + j + 16*q];
    dft4<1>(v[0],v[1],v[2],v[3]);
    #pragma unroll
    for (int r=0;r<4;r++) s[SW2(4*j+r)] = v[r];
  }
  wsync();
  if (act){ // L = 4 : read
    v[0] = s[SW2(j)];
    v[1] = cmul(s[SW2(j+16)], w4);
    v[2] = cmul(s[SW2(j+32)], w4b);
    v[3] = cmul(s[SW2(j+48)], w4c);
  }
  wsync();
  if (act){ // L = 4 : write
    dft4<1>(v[0],v[1],v[2],v[3]);
    #pragma unroll
    for (int r=0;r<4;r++) s[SW2(b4+4*r)] = v[r];
  }
  wsync();
  if (act){ // L = 16 + abs
    v[0] = s[SW2(j)];
    v[1] = cmul(s[SW2(j+16)], w16);
    v[2] = cmul(s[SW2(j+32)], w16b);
    v[3] = cmul(s[SW2(j+48)], w16c);
    dft4<1>(v[0],v[1],v[2],v[3]);
    unsigned short* op = outp + (size_t)arr*40000 + (size_t)n1*64;
    #pragma unroll
    for (int r=0;r<4;r++){
      c2 z = v[r];
      av[r] = sqrtf(z.x*z.x + z.y*z.y) * (1.0f/160000.0f);
      op[j + 16*r] = f2bf(av[r]);
    }
  }
  if (WRITEB){
    wsync();
    if (act){
      #pragma unroll
      for (int q=0;q<4;q++) v[q] = c2{av[q], 0.0f};
      dft4<-1>(v[0],v[1],v[2],v[3]);
      #pragma unroll
      for (int r=0;r<4;r++) s[SW2(4*j+r)] = v[r];
    }
    wsync();
    if (act){ // L = 4 : read
      v[0] = s[SW2(j)];
      v[1] = cmulc(s[SW2(j+16)], w4);
      v[2] = cmulc(s[SW2(j+32)], w4b);
      v[3] = cmulc(s[SW2(j+48)], w4c);
    }
    wsync();
    if (act){ // L = 4 : write
      dft4<-1>(v[0],v[1],v[2],v[3]);
      #pragma unroll
      for (int r=0;r<4;r++) s[SW2(b4+4*r)] = v[r];
    }
    wsync();
    if (act){ // L = 16 + twiddle -> tc
      v[0] = s[SW2(j)];
      v[1] = cmulc(s[SW2(j+16)], w16);
      v[2] = cmulc(s[SW2(j+32)], w16b);
      v[3] = cmulc(s[SW2(j+48)], w16c);
      dft4<-1>(v[0],v[1],v[2],v[3]);
      #pragma unroll
      for (int r=0;r<4;r++){
        int kb = j + 16*r;
        c2 tw = cis(-TWO_PI * (float)(n1*kb) * (1.0f/40000.0f));
        tc[row*G2TF + kb] = cmul(v[r], tw);
      }
    }
    __syncthreads();
    unsigned* op = outB + (size_t)arr*40000;
    if (rows == G2CH){
      for (int e = threadIdx.x; e < 64*G2CH; e += 256){
        int kb = e >> 4, i = e & 15;
        op[kb*625 + n1_0 + i] = pack_bf(tc[i*G2TF + kb]);
      }
    } else {
      for (int e = threadIdx.x; e < 64*rows; e += 256){
        int kb = e / rows, i = e - kb*rows;
        op[kb*625 + n1_0 + i] = pack_bf(tc[i*G2TF + kb]);
      }
    }
  }
}

// ---------------- per-thread inverse 16-FFT + abs (M = 10000 tier) ----------------
// Input [slot][kb<16][n1<625] packed bf16; output Ur[slot][n1<625][n2<16] scalar bf16.
__global__ __launch_bounds__(256) void k_fft16g(const unsigned* __restrict__ inp, unsigned short* __restrict__ outp){
  int gid = blockIdx.x*256 + threadIdx.x;
  int s = gid / 625, n1 = gid - s*625;
  if (s >= 288) return;
  const unsigned* ip = inp + (size_t)s*10000 + n1;
  c2 A[4][4];
  #pragma unroll
  for (int k1=0;k1<4;k1++){
    c2 a0 = unpack_bf(ip[(k1   )*625]);
    c2 a1 = unpack_bf(ip[(k1+ 4)*625]);
    c2 a2 = unpack_bf(ip[(k1+ 8)*625]);
    c2 a3 = unpack_bf(ip[(k1+12)*625]);
    dft4<1>(a0,a1,a2,a3);
    A[k1][0]=a0; A[k1][1]=a1; A[k1][2]=a2; A[k1][3]=a3;
  }
  unsigned short ov[16];
  #pragma unroll
  for (int n0=0;n0<4;n0++){
    c2 w1 = cis(TWO_PI * (float)n0 * (1.0f/16.0f));
    c2 w2 = cmul(w1,w1), w3 = cmul(w2,w1);
    c2 b0 = A[0][n0];
    c2 b1 = cmul(A[1][n0], w1);
    c2 b2 = cmul(A[2][n0], w2);
    c2 b3 = cmul(A[3][n0], w3);
    dft4<1>(b0,b1,b2,b3);
    ov[n0   ] = f2bf(sqrtf(b0.x*b0.x+b0.y*b0.y)*(1.0f/160000.0f));
    ov[n0+ 4] = f2bf(sqrtf(b1.x*b1.x+b1.y*b1.y)*(1.0f/160000.0f));
    ov[n0+ 8] = f2bf(sqrtf(b2.x*b2.x+b2.y*b2.y)*(1.0f/160000.0f));
    ov[n0+12] = f2bf(sqrtf(b3.x*b3.x+b3.y*b3.y)*(1.0f/160000.0f));
  }
  unsigned short* op = outp + (size_t)s*10000 + (size_t)n1*16;
  #pragma unroll
  for (int n=0;n<16;n++) op[n] = ov[n];
}

// ---------------- 625-point row FFT (radix-5 Stockham), c2-packed LDS ----------------
// FILT: 0 none, 1 psi1 (FOLD/QPH phases), 2 psi2 (decode via launch params),
//       3 psi2 from completed 2-phase spectra (c0), 4 psi2 table-driven (dec).
template<int S, int FILT, int TW, int PIN, int POUT, int NB2, int NBI, int FOLD, int QPH>
__global__ __launch_bounds__(128) void k_fft625(const void* __restrict__ inpv, void* __restrict__ outpv,
                                                const c2* __restrict__ Wg,
                                                int j1off, int BLK, int nj2, int j2base, int istr,
                                                int scBase, int kamax, const int* __restrict__ ftab){
  __shared__ c2 l0[625], l1[625];
  int g = blockIdx.x;
  int i = g / NB2, kb = g - i*NB2;
  int j = threadIdx.x;
  const c2* ipc = (const c2*)inpv;
  const unsigned* ipu = (const unsigned*)inpv;
  size_t ibase;
  int j1 = 0, j2 = 0;
  if (FILT == 0){
    ibase = (size_t)i*(625ULL*(size_t)NB2) + (size_t)kb*NA;
  } else if (FILT == 1){
    int bt = i / BLK; j1 = j1off + (i - bt*BLK);
    ibase = (size_t)bt*(625ULL*(size_t)NBI);
  } else if (FILT == 2){
    int npb = BLK*nj2;
    int bt = i / npb, rr = i - bt*npb;
    int jloc = rr / nj2; j2 = j2base + (rr - jloc*nj2);
    int islot = bt*istr + j1off + jloc;
    ibase = (size_t)islot*(625ULL*(size_t)NBI);
  } else if (FILT == 4){
    int v = ftab[i];
    int islot = v & 0xFFFF;
    j2 = v >> 16;
    ibase = (size_t)islot*(625ULL*(size_t)NBI);
  } else { // FILT 3: completed-spectrum slot space (40000 each)
    int npb = BLK*nj2;
    int bt = i / npb, rr = i - bt*npb;
    int jloc = rr / nj2; j2 = j2base + (rr - jloc*nj2);
    int islot = bt*BLK + jloc;
    ibase = (size_t)islot*40000ULL;
  }
  float xi = 0.0f, sig = 0.0f, inv2s = 0.0f;
  int klo = 0, khi = 0;
  const float fscale = ((FILT == 2 || FILT == 4) && NBI == 64) ? 4.0f : 1.0f;
  if (FILT != 0){
    if (FILT == 1){ xi = 0.4f * exp2f(-(float)j1 * 0.0625f); sig = xi * 0.04427378243f; }
    else          { xi = 0.4f * exp2f(-(float)j2);           sig = 0.35f * xi; }
    inv2s = 0.5f / (sig*sig);
    klo = (int)((xi - 6.0f*sig) * (float)TLEN); if (klo < 0) klo = 0;
    khi = (int)((xi + 6.0f*sig) * (float)TLEN) + 1; if (khi > TLEN/2 - 1) khi = TLEN/2 - 1;
    if (FILT != 3 && !FOLD){
      if (khi > 625*NB2 - 1) khi = 625*NB2 - 1;
    }
  }
  c2 a[5], b[5];
  if (j < 125){
    if (FILT == 0){
      #pragma unroll
      for (int q=0;q<5;q++){
        size_t idx = ibase + j + 125*q;
        a[q] = PIN ? unpack_bf(ipu[idx]) : ipc[idx];
      }
      dft5<S>(a, b);
    } else if (FILT == 3){
      bool any = false;
      #pragma unroll
      for (int q=0;q<5;q++){
        int ka = j + 125*q;
        int k = kb + NB2*ka;
        float p0 = 0.0f, p1 = 0.0f;
        if (k >= klo && k <= khi){
          float d = (float)k * (1.0f/(float)TLEN) - xi;
          p0 = __expf(-d*d*inv2s); any = true;
        }
        int k1 = k + 40000;
        if (k1 >= klo && k1 <= khi){
          float d = (float)k1 * (1.0f/(float)TLEN) - xi;
          p1 = __expf(-d*d*inv2s); any = true;
        }
        c2 val = c2{0.0f, 0.0f};
        if (p0 != 0.0f || p1 != 0.0f){
          size_t kidx = (size_t)(k & 63)*625 + (size_t)(k >> 6);
          c2 B0 = unpack_bf(ipu[ibase + kidx]);
          c2 B2 = unpack_bf(ipu[ibase + 1280000ULL + kidx]);
          c2 tw = cis(-TWO_PI * (float)k * (1.0f/80000.0f));
          c2 twB2 = cmul(tw, B2);
          c2 Hk = c2{2.0f*(B0.x + twB2.x), 2.0f*(B0.y + twB2.y)};
          c2 Hb = c2{2.0f*(B0.x - twB2.x), 2.0f*(B0.y - twB2.y)};
          if (p1 != 0.0f && k > 0){
            int qi = 40000 - k;
            size_t qidx = (size_t)(qi & 63)*625 + (size_t)(qi >> 6);
            c2 C0 = unpack_bf(ipu[ibase + qidx]);
            c2 C2 = unpack_bf(ipu[ibase + 1280000ULL + qidx]);
            c2 ctwC2 = cmulc(C2, tw);
            c2 Hq = c2{2.0f*(C0.x - ctwC2.x), 2.0f*(C0.y - ctwC2.y)};
            Hb.x -= Hq.x;  Hb.y += Hq.y;
          }
          if (QPH == 0){
            val = c2{p0*Hk.x + p1*Hb.x, p0*Hk.y + p1*Hb.y};
          } else {
            c2 t2 = c2{p0*Hk.x - p1*Hb.x, p0*Hk.y - p1*Hb.y};
            val = cmulc(t2, tw);
          }
        }
        a[q] = val;
      }
      if (any){
        dft5<S>(a, b);
      } else {
        #pragma unroll
        for (int r=0;r<5;r++) b[r] = c2{0.0f,0.0f};
      }
    } else {  // FILT 1, 2 or 4
      bool any = false;
      #pragma unroll
      for (int q=0;q<5;q++){
        int ka = j + 125*q;
        int k = kb + NB2*ka;
        c2 val = c2{0.0f, 0.0f};
        if (k >= klo && k <= khi){
          size_t idx = ibase + (size_t)(k % NBI)*NA + (size_t)(k / NBI);
          val = PIN ? unpack_bf(ipu[idx]) : ipc[idx];
          float d = (float)k * (1.0f/(float)TLEN) - xi;
          float f = fscale * __expf(-d*d*inv2s);
          val.x *= f; val.y *= f;
          any = true;
        }
        if (FILT == 1 && FOLD){
          int k1 = k + 40000;
          if (k1 >= klo && k1 <= khi){
            size_t idx1 = ibase + (size_t)(k1 % NBI)*NA + (size_t)(k1 / NBI);
            c2 v1 = PIN ? unpack_bf(ipu[idx1]) : ipc[idx1];
            float d = (float)k1 * (1.0f/(float)TLEN) - xi;
            float f1 = __expf(-d*d*inv2s);
            v1.x *= f1; v1.y *= f1;
            val = QPH ? csub(val, v1) : cadd(val, v1);
            any = true;
          }
        }
        if (FILT == 1 && FOLD && QPH){
          c2 tww = cis(TWO_PI * (float)k * (1.0f/80000.0f));
          val = cmul(tww, val);
        }
        a[q] = val;
      }
      if (any){
        dft5<S>(a, b);
      } else {
        #pragma unroll
        for (int r=0;r<5;r++) b[r] = c2{0.0f,0.0f};
      }
    }
    #pragma unroll
    for (int r=0;r<5;r++) l0[5*j + r] = b[r];
  }
  __syncthreads();
  if (j < 125){ // L = 5
    int k = j % 5;
    c2 w  = Wg[25*k];  if (S<0) w.y  = -w.y;
    c2 w2 = Wg[50*k];  if (S<0) w2.y = -w2.y;
    c2 w3 = Wg[75*k];  if (S<0) w3.y = -w3.y;
    c2 w4 = Wg[100*k]; if (S<0) w4.y = -w4.y;
    a[0] = l0[j];
    a[1] = cmul(l0[j+125], w);
    a[2] = cmul(l0[j+250], w2);
    a[3] = cmul(l0[j+375], w3);
    a[4] = cmul(l0[j+500], w4);
    dft5<S>(a, b);
    int base = 5*(j-k)+k;
    #pragma unroll
    for (int r=0;r<5;r++) l1[base + 5*r] = b[r];
  }
  __syncthreads();
  if (j < 125){ // L = 25
    int k = j % 25;
    c2 w  = Wg[5*k];   if (S<0) w.y  = -w.y;
    c2 w2 = Wg[10*k];  if (S<0) w2.y = -w2.y;
    c2 w3 = Wg[15*k];  if (S<0) w3.y = -w3.y;
    c2 w4 = Wg[20*k];  if (S<0) w4.y = -w4.y;
    a[0] = l1[j];
    a[1] = cmul(l1[j+125], w);
    a[2] = cmul(l1[j+250], w2);
    a[3] = cmul(l1[j+375], w3);
    a[4] = cmul(l1[j+500], w4);
    dft5<S>(a, b);
    int base = 5*(j-k)+k;
    #pragma unroll
    for (int r=0;r<5;r++) l0[base + 25*r] = b[r];
  }
  __syncthreads();
  if (j < 125){ // L = 125
    c2 w = Wg[j]; if (S<0) w.y = -w.y;
    c2 w2 = cmul(w,w), w3 = cmul(w2,w), w4 = cmul(w2,w2);
    a[0] = l0[j];
    a[1] = cmul(l0[j+125], w);
    a[2] = cmul(l0[j+250], w2);
    a[3] = cmul(l0[j+375], w3);
    a[4] = cmul(l0[j+500], w4);
    dft5<S>(a, b);
    size_t obase = (size_t)(scBase + i)*(625ULL*(size_t)NB2) + (size_t)kb*NA;
    if (TW){
      const float invM = 1.0f/(625.0f*(float)NB2);
      c2 twb = cis((float)S * TWO_PI * (float)(j*kb)   * invM);
      c2 tws = cis((float)S * TWO_PI * (float)(125*kb) * invM);
      #pragma unroll
      for (int r=0;r<5;r++){
        int n1 = j + 125*r;
        c2 z = cmul(b[r], twb);
        if (POUT) ((unsigned*)outpv)[obase + n1] = pack_bf(z);
        else      ((c2*)outpv)[obase + n1] = z;
        twb = cmul(twb, tws);
      }
    } else {
      #pragma unroll
      for (int r=0;r<5;r++){
        int n1 = j + 125*r;
        if (n1 <= kamax){
          if (POUT) ((unsigned*)outpv)[obase + n1] = pack_bf(b[r]);
          else      ((c2*)outpv)[obase + n1] = b[r];
        }
      }
    }
  }
}

// ---------------- complex transpose (x-chain only) ----------------
__global__ __launch_bounds__(256) void k_transpose(const c2* __restrict__ in, c2* __restrict__ out,
                                                   int R, int C, int tilesR, int tilesC){
  __shared__ c2 tile[32][33];
  int bi = blockIdx.x;
  int arr = bi / (tilesR*tilesC);
  int tt = bi - arr*(tilesR*tilesC);
  int tr = tt / tilesC, tc = tt - tr*tilesC;
  const c2* ip = in + (size_t)arr*TLEN;
  c2* op = out + (size_t)arr*TLEN;
  int tx = threadIdx.x & 31, ty = threadIdx.x >> 5;
  #pragma unroll
  for (int i=0;i<4;i++){
    int r = tr*32 + ty + i*8, cc = tc*32 + tx;
    if (r < R && cc < C) tile[ty+i*8][tx] = ip[(size_t)r*C + cc];
  }
  __syncthreads();
  #pragma unroll
  for (int i=0;i<4;i++){
    int r = tc*32 + ty + i*8, cc = tr*32 + tx;
    if (r < C && cc < R) op[(size_t)r*R + cc] = tile[tx][ty+i*8];
  }
}

// ---------------- Gaussian lowpass + decimate-by-64, natural layout (S0 only) ----------------
__global__ __launch_bounds__(256) void k_conv(const float* __restrict__ inp, float* __restrict__ S){
  __shared__ float w[NTAP];
  for (int i=threadIdx.x; i<NTAP; i+=256){
    float d = (float)(i - KC);
    w[i] = 0.015666427f * __expf(-7.7106284e-4f * d * d);
  }
  __syncthreads();
  int g = blockIdx.x;
  int arr = g / 10;
  int t = (g - arr*10)*256 + threadIdx.x;
  if (t >= TD) return;
  int srow = arr * SROWS;
  const float* ip = inp + (size_t)arr*TLEN;
  float acc = 0.0f;
  int n = 64*t - KC; if (n < 0) n += TLEN;
  for (int m=0;m<NTAP;m++){
    acc += ip[n] * w[m];
    n++; if (n == TLEN) n = 0;
  }
  S[(size_t)srow*TD + t] = acc;
}

// ---------------- decimated conv (D=4): input Ur_dec[n1<625][n2<64], M=40000 ----------------
#define C2NU  5000
#define C2USZ 5312
template<int MODE>
__global__ __launch_bounds__(256) void k_conv2d(const unsigned short* __restrict__ inp, float* __restrict__ S,
                                                int j1off, int BLK, const int* __restrict__ srowTab){
  __shared__ float u[C2USZ];
  __shared__ float w[72];
  if (threadIdx.x < 65){
    float d = 4.0f * (float)((int)threadIdx.x - 32);
    w[threadIdx.x] = 0.062665708f * __expf(-7.7106284e-4f * d * d);
  }
  int g = blockIdx.x;
  int arr = g / 10;
  int b = g - arr*10;
  int mlo = 4000*b - 32;
  int n2_0 = (mlo >= 0) ? (mlo/625) : -1;
  const unsigned short* ip = inp + (size_t)arr*40000;
  for (int e = threadIdx.x; e < C2NU; e += 256){
    int n1 = e >> 3, c = e & 7;
    int n2 = (n2_0 + c) & 63;
    u[SW16(n1 + 625*c)] = bf2f(ip[n1*64 + n2]);
  }
  __syncthreads();
  int tl = threadIdx.x;
  if (tl >= 250) return;
  int t = 250*b + tl;
  int srow;
  if (MODE == 1){
    int a2 = arr / BLK; int j1 = j1off + (arr - a2*BLK);
    srow = a2*SROWS + 1 + j1;
  } else {
    srow = srowTab[arr];
  }
  int base = (4000*b - 32 - 625*n2_0) + 16*tl;
  float acc = 0.0f;
  #pragma unroll 5
  for (int m=0;m<65;m++){
    acc += u[SW16(base + m)] * w[m];
  }
  S[(size_t)srow*TD + t] = acc;
}

// ---------------- decimated conv (D=16): input Ur10k[n1<625][n2<16], M=10000 ----------------
#define CQ_USZ 2344
__global__ __launch_bounds__(256) void k_conv2q(const unsigned short* __restrict__ inp, float* __restrict__ S,
                                                const int* __restrict__ srowTab){
  __shared__ float u[CQ_USZ];
  __shared__ float w[20];
  if (threadIdx.x < 17){
    float d = 16.0f * (float)((int)threadIdx.x - 8);
    w[threadIdx.x] = 0.25066283f * __expf(-7.7106284e-4f * d * d);
  }
  int g = blockIdx.x;
  int slot = g / 10;
  int b = g - slot*10;
  int mlo = 1000*b - 8;
  int n2_0 = (mlo >= 0) ? (mlo/625) : -1;
  const unsigned short* ip = inp + (size_t)slot*10000;
  for (int e = threadIdx.x; e < 1875; e += 256){
    int c = e / 625, n1 = e - c*625;
    int n2 = (n2_0 + c) & 15;
    u[SW2(n1 + 625*c)] = bf2f(ip[n1*16 + n2]);
  }
  __syncthreads();
  int tl = threadIdx.x;
  if (tl >= 250) return;
  int t = 250*b + tl;
  int srow = srowTab[slot];
  int base = (1000*b - 8 - 625*n2_0) + 4*tl;
  float acc = 0.0f;
  #pragma unroll
  for (int m=0;m<17;m++){
    acc += u[SW2(base + m)] * w[m];
  }
  S[(size_t)srow*TD + t] = acc;
}

// ---------------- 2-phase decimated conv (D=2) for c0 j2=1 paths ----------------
__global__ __launch_bounds__(256) void k_conv2e(const unsigned short* __restrict__ Ue,
                                                const unsigned short* __restrict__ Uo,
                                                float* __restrict__ S){
  __shared__ float ue[C2USZ], uo[C2USZ];
  __shared__ float we[72], wo[72];
  if (threadIdx.x < 65){
    float d = 4.0f*(float)((int)threadIdx.x) - 128.0f;
    we[threadIdx.x] = 0.031332854f * __expf(-7.7106284e-4f * d * d);
  }
  if (threadIdx.x >= 128 && threadIdx.x < 192){
    int h = (int)threadIdx.x - 128;
    float d = 4.0f*(float)h - 126.0f;
    wo[h] = 0.031332854f * __expf(-7.7106284e-4f * d * d);
  }
  int g = blockIdx.x;
  int path = g / 10;
  int b = g - path*10;
  int mlo = 4000*b - 32;
  int n2_0 = (mlo >= 0) ? (mlo/625) : -1;
  const unsigned short* ipe = Ue + (size_t)path*40000;
  const unsigned short* ipo = Uo + (size_t)path*40000;
  for (int e = threadIdx.x; e < C2NU; e += 256){
    int n1 = e >> 3, c = e & 7;
    int n2 = (n2_0 + c) & 63;
    ue[SW16(n1 + 625*c)] = bf2f(ipe[n1*64 + n2]);
    uo[SW16(n1 + 625*c)] = bf2f(ipo[n1*64 + n2]);
  }
  __syncthreads();
  int tl = threadIdx.x;
  if (tl >= 250) return;
  int t = 250*b + tl;
  int arr = path >> 4;
  int j1  = path & 15;
  int srow = arr*SROWS + 97 + 5*j1;
  int base = (4000*b - 32 - 625*n2_0) + 16*tl;
  float acc = 0.0f;
  #pragma unroll 5
  for (int m=0;m<65;m++){
    acc += ue[SW16(base + m)] * we[m];
  }
  #pragma unroll 4
  for (int m=0;m<64;m++){
    acc += uo[SW16(base + m)] * wo[m];
  }
  S[(size_t)srow*TD + t] = acc;
}

// ---------------- global min/max + finalize ----------------
__global__ __launch_bounds__(256) void k_minmax1(const float* __restrict__ S, int n, float* pmn, float* pmx){
  __shared__ float smn[256], smx[256];
  float mn = 3.4028235e38f, mx = -3.4028235e38f;
  for (size_t i = (size_t)blockIdx.x*256 + threadIdx.x; i < (size_t)n; i += (size_t)gridDim.x*256){
    float v = S[i]; mn = fminf(mn,v); mx = fmaxf(mx,v);
  }
  smn[threadIdx.x]=mn; smx[threadIdx.x]=mx; __syncthreads();
  for (int s=128;s>0;s>>=1){
    if ((int)threadIdx.x < s){
      smn[threadIdx.x]=fminf(smn[threadIdx.x],smn[threadIdx.x+s]);
      smx[threadIdx.x]=fmaxf(smx[threadIdx.x],smx[threadIdx.x+s]);
    }
    __syncthreads();
  }
  if (threadIdx.x==0){ pmn[blockIdx.x]=smn[0]; pmx[blockIdx.x]=smx[0]; }
}
__global__ __launch_bounds__(256) void k_minmax2(const float* __restrict__ pmn, const float* __restrict__ pmx,
                                                 int nb, float* scal){
  __shared__ float smn[256], smx[256];
  float mn = 3.4028235e38f, mx = -3.4028235e38f;
  for (int i = threadIdx.x; i < nb; i += 256){ mn = fminf(mn,pmn[i]); mx = fmaxf(mx,pmx[i]); }
  smn[threadIdx.x]=mn; smx[threadIdx.x]=mx; __syncthreads();
  for (int s=128;s>0;s>>=1){
    if ((int)threadIdx.x < s){
      smn[threadIdx.x]=fminf(smn[threadIdx.x],smn[threadIdx.x+s]);
      smx[threadIdx.x]=fmaxf(smx[threadIdx.x],smx[threadIdx.x+s]);
    }
    __syncthreads();
  }
  if (threadIdx.x==0){ scal[0]=smn[0]; scal[1]=smx[0]; }
}
__global__ __launch_bounds__(256) void k_final(const float* __restrict__ S, const float* __restrict__ scal,
                                               float* __restrict__ out, int n){
  int i = blockIdx.x*256 + threadIdx.x;
  if (i >= n) return;
  float mn = scal[0];
  float r = scal[1] - mn;
  if (r == 0.0f) r = 1.0f;
  int half = SROWS*TD;
  int a = i / half; int rest = i - a*half;
  out[i] = (S[(size_t)(a & 1)*half + rest] - mn) / r;
}

extern "C" void kernel_launch(void* const* d_in, const int* in_sizes, int n_in,
                              void* d_out, int out_size, void* d_ws, size_t ws_size,
                              hipStream_t stream){
  (void)in_sizes; (void)n_in;
  const float* x = (const float*)d_in[0];

  // Xf 2.56 + A1 35.84 + B 35.84 + U1h 35.84 + A2 47.36 + Ur 23.68 + Sb 6.74 + misc
  {
    size_t need = 2560000ULL + 35840000ULL + 35840000ULL + 35840000ULL
                + 47360000ULL + 23680000ULL + 6740000ULL + 65536ULL;
    if (ws_size < need) return;
  }

  char* p = (char*)d_ws;
  auto carve = [&](size_t bytes)->void*{ void* r = (void*)p; p += (bytes + 255) & ~(size_t)255; return r; };
  c2*             Xf  = (c2*)carve(2ULL*TLEN*sizeof(c2));
  unsigned*       A1  = (unsigned*)carve(224ULL*40000*4);    // 0-31 c0e, 32-63 c0o, 64-223 dec
  unsigned*       B   = (unsigned*)carve(224ULL*40000*4);    // first-stage fwd, same slot map
  unsigned*       U1h = (unsigned*)carve(224ULL*40000*4);    // completed spectra, same slot map
  unsigned*       A2  = (unsigned*)carve(224ULL*40000*4 + 288ULL*10000*4); // 40k tier + 10k tier
  unsigned short* Ur  = (unsigned short*)carve(224ULL*40000*2 + 288ULL*10000*2);
  float*          Sb  = (float*)carve(2ULL*SROWS*TD*sizeof(float));
  c2*             Wg  = (c2*)carve(625*sizeof(c2));
  int*            tab = (int*)carve(768*4);
  float*          pmn = (float*)carve(512*4);
  float*          pmx = (float*)carve(512*4);
  float*          scal = (float*)carve(256);

  unsigned*       A2t = A2 + 224ULL*40000;        // 10k tier spectra
  unsigned short* Urt = Ur + 224ULL*40000;        // 10k tier magnitudes

  k_wlut<<<3, 256, 0, stream>>>(Wg);
  k_ptab<<<3, 256, 0, stream>>>(tab);

  // ---- forward FFT of x -> Xf (A2 reused as c2 scratch; U1h as c2 scratch) ----
  k_fft256<-1,2,0><<<2*NA, 64, 0, stream>>>((const void*)x, (void*)A2);
  k_transpose<<<2*20*8, 256, 0, stream>>>((c2*)A2, (c2*)U1h, NA, NB, 20, 8);
  k_fft625<-1,0,0,0,0,256,256,0,0><<<2*NB, 128, 0, stream>>>((const void*)U1h, (void*)Xf, Wg, 0,0,0,0,0,0, 314, nullptr);
  // ---- S0 ----
  k_conv<<<2*10, 256, 0, stream>>>(x, Sb);

  // ================= order-1 (all decimated) =================
  k_fft625<1,1,1,0,1,64,256,1,0><<<32*64, 128, 0, stream>>>((const void*)Xf, (void*)A1, Wg, 0,16,0,0,0,0, 624, nullptr);
  k_fft625<1,1,1,0,1,64,256,1,1><<<32*64, 128, 0, stream>>>((const void*)Xf, (void*)A1, Wg, 0,16,0,0,0,32, 624, nullptr);
  k_fft625<1,1,1,0,1,64,256,0,0><<<160*64, 128, 0, stream>>>((const void*)Xf, (void*)A1, Wg, 16,80,0,0,0,64, 624, nullptr);
  k_fft64g<1><<<224*G2N, 256, 0, stream>>>(A1, Ur, B);
  k_conv2d<1><<<32*10, 256, 0, stream>>>(Ur, Sb, 0, 16, (const int*)nullptr);
  k_conv2d<1><<<160*10, 256, 0, stream>>>(Ur + 64ULL*40000, Sb, 16, 80, (const int*)nullptr);
  // second stage forward over ALL 224 slots -> completed spectra in U1h
  k_fft625<-1,0,0,1,1,64,64,0,0><<<224*64, 128, 0, stream>>>((const void*)B, (void*)U1h, Wg, 0,0,0,0,0,0, 624, nullptr);

  // ================= order-2, M=40000 tier (j2 <= 3) =================
  // dec j2<=3 (96 paths, table) -> A2 slots 128-223
  k_fft625<1,4,1,1,1,64,64,0,0><<<96*64, 128, 0, stream>>>((const void*)(U1h + 64ULL*40000), (void*)A2, Wg,
                                                           0,0,0,0,0, 128, 624, tab + 448);
  // c0 j2 in {2,3} -> slots 64-127
  k_fft625<1,3,1,1,1,64,64,0,0><<<64*64, 128, 0, stream>>>((const void*)U1h, (void*)A2, Wg, 0,16,2,2,16, 64, 624, nullptr);
  // c0 j2=1, two phases -> slots 0-31 / 32-63
  k_fft625<1,3,1,1,1,64,64,0,0><<<32*64, 128, 0, stream>>>((const void*)U1h, (void*)A2, Wg, 0,16,1,1,16, 0, 624, nullptr);
  k_fft625<1,3,1,1,1,64,64,0,1><<<32*64, 128, 0, stream>>>((const void*)U1h, (void*)A2, Wg, 0,16,1,1,16, 32, 624, nullptr);
  k_fft64g<0><<<224*G2N, 256, 0, stream>>>(A2, Ur, (unsigned*)nullptr);
  k_conv2e<<<32*10, 256, 0, stream>>>(Ur, Ur + 32ULL*40000, Sb);
  k_conv2d<3><<<160*10, 256, 0, stream>>>(Ur + 64ULL*40000, Sb, 0, 0, tab);

  // ================= order-2, M=10000 tier (j2 >= 4) =================
  // c0 j2 in {4,5} -> 10k slots 0-63
  k_fft625<1,3,1,1,1,16,64,0,0><<<64*16, 128, 0, stream>>>((const void*)U1h, (void*)A2t, Wg, 0,16,2,4,16, 0, 624, nullptr);
  // dec j2>=4 (224 paths, table) -> 10k slots 64-287
  k_fft625<1,4,1,1,1,16,64,0,0><<<224*16, 128, 0, stream>>>((const void*)(U1h + 64ULL*40000), (void*)A2t, Wg,
                                                            0,0,0,0,0, 64, 624, tab + 544);
  k_fft16g<<<704, 256, 0, stream>>>(A2t, Urt);
  k_conv2q<<<288*10, 256, 0, stream>>>(Urt, Sb, tab + 160);

  // ---- global min-max normalize (standardize cancels) + tile(3,1,1) ----
  k_minmax1<<<512, 256, 0, stream>>>(Sb, 2*SROWS*TD, pmn, pmx);
  k_minmax2<<<1, 256, 0, stream>>>(pmn, pmx, 512, scal);
  k_final<<<(out_size+255)/256, 256, 0, stream>>>(Sb, scal, (float*)d_out, out_size);
}